// Round 11
// baseline (1977.799 us; speedup 1.0000x reference)
//
#include <hip/hip_runtime.h>

#define BATCH 4
#define NPTS  16384
#define CH    128
#define KNN   16

// ---- fine grid: 64^3 cells of 0.25 ----
#define G      64
#define GRID3  (G * G * G)          // 262144 cells per batch (= 2^18)
#define GW     0.25f
#define GINVW  4.0f
#define GORIG  (-8.0f)
#define OCCW   (GRID3 / 32)         // 8192 occupancy words per batch

#define QWAVES 1024                 // waves per batch for knn
#define QPW    (NPTS / QWAVES)      // 16 queries per wave (interleaved)

// ---------------- workspace layout (bytes) ----------------
#define XT_OFF    0
#define HT_OFF    33554432
#define CNT_OFF   33554432
#define CUR_OFF   37748736
#define HDR_OFF   41943040
#define OCC_OFF   50331648
#define SPTS_OFF  50462720
#define GCTR_OFF  51511296
#define IDX_OFF   67108864
#define PART_OFF  71303168
#define STATS_OFF 75497472

__device__ __forceinline__ int cell1(float v) {
    int c = (int)floorf((v - GORIG) * GINVW);
    return min(G - 1, max(0, c));
}

__device__ __forceinline__ float axdist(float q, int c) {
    const float lo = GORIG + c * GW;
    return fmaxf(fmaxf(lo - q, q - (lo + GW)), 0.0f);
}

__device__ __forceinline__ bool lexlt(float d1, int i1, float d2, int i2) {
    return (d1 < d2) || (d1 == d2 && i1 < i2);
}

__device__ __forceinline__ void insert_lex(float (&dq)[KNN], int (&iq)[KNN], float d, int oi) {
    float cd = d; int ci = oi;
#pragma unroll
    for (int t = KNN - 1; t >= 1; --t) {
        if (lexlt(cd, ci, dq[t - 1], iq[t - 1])) {
            dq[t] = dq[t - 1]; iq[t] = iq[t - 1];
            if (t == 1) { dq[0] = cd; iq[0] = ci; }
        } else {
            dq[t] = cd; iq[t] = ci;
            break;
        }
    }
}

// wave-wide argmin extraction of per-lane pending candidates into dq/iq.
// After this, all pending are consumed (provably lex->= dq[15], discarded).
__device__ __forceinline__ void wave_flush(float& pd, int& poi, int& cnum, int lane,
                                           float (&dq)[KNN], int (&iq)[KNN]) {
    if (cnum == 0) return;
#pragma unroll
    for (int it = 0; it < KNN; ++it) {
        float md = pd; int mi = poi; int ml = lane;
#pragma unroll
        for (int off = 1; off < 64; off <<= 1) {
            const float od = __shfl_xor(md, off);
            const int  omi = __shfl_xor(mi, off);
            const int  oml = __shfl_xor(ml, off);
            if (lexlt(od, omi, md, mi)) { md = od; mi = omi; ml = oml; }
        }
        if (!lexlt(md, mi, dq[KNN - 1], iq[KNN - 1])) break;
        insert_lex(dq, iq, md, mi);
        if (lane == ml) { pd = 3.0e38f; poi = 0x7fffffff; }
    }
    pd = 3.0e38f; poi = 0x7fffffff;   // discard remainder (all lex->= dq[15])
    cnum = 0;
}

// append candidate range [a0,e0) minus seed window [w0,w0+64); each candidate
// lands in one lane's pending register pair; flush when 64 are pending.
__device__ __forceinline__ void wave_append(const float4* __restrict__ pts,
                                            int a0, int e0, int w0,
                                            float qx, float qy, float qz, int lane,
                                            float& pd, int& poi, int& cnum,
                                            float (&dq)[KNN], int (&iq)[KNN]) {
#pragma unroll
    for (int part = 0; part < 2; ++part) {
        int a = part ? max(a0, w0 + 64) : a0;
        const int e = part ? e0 : min(e0, w0);
        int c = e - a;
        while (c > 0) {
            const int t = min(c, 64 - cnum);
            if (lane >= cnum && lane < cnum + t) {
                const float4 pp = pts[a + lane - cnum];
                const float ddx = __fsub_rn(qx, pp.x);
                const float ddy = __fsub_rn(qy, pp.y);
                const float ddz = __fsub_rn(qz, pp.z);
                pd  = __fadd_rn(__fadd_rn(__fmul_rn(ddx, ddx), __fmul_rn(ddy, ddy)),
                                __fmul_rn(ddz, ddz));
                poi = __float_as_int(pp.w);
            }
            c -= t; a += t; cnum += t;
            if (cnum == 64) wave_flush(pd, poi, cnum, lane, dq, iq);
        }
    }
}

// ---------------------------------------------------------------------------
// 0) zero grid counters (counts+cursor contiguous) and per-batch allocators
__global__ __launch_bounds__(256) void zero_kernel(int* __restrict__ p, int n,
                                                   int* __restrict__ gctr) {
    int i = blockIdx.x * 256 + threadIdx.x;
    if (i < BATCH) gctr[i] = 0;
    const int stride = gridDim.x * 256;
    for (; i < n; i += stride) p[i] = 0;
}

// ---------------------------------------------------------------------------
// 1) transpose x [B,CH,N] -> xt [B,N,CH]
__global__ __launch_bounds__(256) void transpose_kernel(const float* __restrict__ x,
                                                        float* __restrict__ xt) {
    __shared__ float t[32][33];
    const int b  = blockIdx.z;
    const int c0 = blockIdx.y * 32;
    const int n0 = blockIdx.x * 32;
    const int tx = threadIdx.x, ty = threadIdx.y;   // block (32,8)
#pragma unroll
    for (int i = 0; i < 4; ++i)
        t[ty + 8 * i][tx] = x[((size_t)b * CH + c0 + ty + 8 * i) * NPTS + n0 + tx];
    __syncthreads();
#pragma unroll
    for (int i = 0; i < 4; ++i)
        xt[((size_t)b * NPTS + n0 + ty + 8 * i) * CH + c0 + tx] = t[tx][ty + 8 * i];
}

// ---------------------------------------------------------------------------
// 2a) count points per cell (linear cid = (z*G+y)*G+x)
__global__ __launch_bounds__(256) void count_kernel(const float* __restrict__ xyz,
                                                    int* __restrict__ counts) {
    const int b = blockIdx.y;
    const int i = blockIdx.x * 256 + threadIdx.x;
    const float* p = xyz + ((size_t)b * NPTS + i) * 3;
    const int c = (cell1(p[2]) * G + cell1(p[1])) * G + cell1(p[0]);
    atomicAdd(&counts[((size_t)b << 18) + c], 1);
}

// 2b) per-cell (start,count) headers + z-major occupancy (R4-proven)
__global__ __launch_bounds__(256) void cellhdr_kernel(const int* __restrict__ counts,
                                                      int2* __restrict__ hdr,
                                                      unsigned int* __restrict__ occ,
                                                      int* __restrict__ gctr) {
    const int cid  = blockIdx.x * 256 + threadIdx.x;
    const int b    = cid >> 18;
    const int lane = threadIdx.x & 63;
    const int c    = counts[cid];

    int incl = c;
#pragma unroll
    for (int off = 1; off < 64; off <<= 1) {
        int t = __shfl_up(incl, off);
        if (lane >= off) incl += t;
    }
    const int excl = incl - c;
    const int tot  = __shfl(incl, 63);

    const unsigned long long ball = __ballot(c > 0);
    if (lane == 0) {
        const int w = cid >> 5;
        occ[w]     = (unsigned int)ball;
        occ[w + 1] = (unsigned int)(ball >> 32);
    }

    int base = 0;
    if (lane == 63) base = atomicAdd(&gctr[b], tot);
    base = __shfl(base, 63);

    if (c > 0) hdr[cid] = make_int2(base + excl, c);
}

// 2c) scatter points into cell-grouped order, original idx in .w
__global__ __launch_bounds__(256) void scatter_kernel(const float* __restrict__ xyz,
                                                      const int2* __restrict__ hdr,
                                                      int* __restrict__ cursor,
                                                      float4* __restrict__ spts) {
    const int b = blockIdx.y;
    const int i = blockIdx.x * 256 + threadIdx.x;
    const float* p = xyz + ((size_t)b * NPTS + i) * 3;
    const float x = p[0], y = p[1], z = p[2];
    const int c = (cell1(z) * G + cell1(y)) * G + cell1(x);
    const int pos = hdr[((size_t)b << 18) + c].x + atomicAdd(&cursor[((size_t)b << 18) + c], 1);
    spts[(size_t)b * NPTS + pos] = make_float4(x, y, z, __int_as_float(i));
}

// ---------------------------------------------------------------------------
// 2d) exact KNN: ONE QUERY PER WAVE (divergence-free), register-resident.
//     Candidates pend in per-lane registers (no LDS buffer, no scratch);
//     flush = wave argmin extraction via shfl_xor. Seed = bitonic sort64 of
//     window [s&~63,+64), interval-subtracted from cell scans (no dups).
//     Selection exact lex-(d, original idx) == jax.lax.top_k.
__global__ __launch_bounds__(256) void knn_wave_kernel(const float4* __restrict__ spts,
                                                       const int2* __restrict__ hdr,
                                                       const unsigned int* __restrict__ occ,
                                                       int* __restrict__ idx_out) {
    __shared__ unsigned int socc[OCCW];    // 32 KB occupancy
    const int b   = blockIdx.y;
    const int tid = threadIdx.x;
    for (int i = tid; i < OCCW; i += 256) socc[i] = occ[(size_t)b * OCCW + i];
    __syncthreads();

    const int widx = tid >> 6;
    const int lane = tid & 63;
    const int wid  = blockIdx.x * 4 + widx;          // 0..QWAVES-1
    const int2* hb = hdr + ((size_t)b << 18);
    const float4* pts = spts + (size_t)b * NPTS;

    for (int q = 0; q < QPW; ++q) {
        const int s = wid + q * QWAVES;              // interleaved assignment
        const float4 P = pts[s];
        const float qx = P.x, qy = P.y, qz = P.z;
        const int qi = __float_as_int(P.w);
        const int cx = cell1(qx), cy = cell1(qy), cz = cell1(qz);

        float dq[KNN]; int iq[KNN];

        // ---- seed: window [w0, w0+64), bitonic sort64 across lanes ----
        const int w0 = s & ~63;
        {
            const float4 pp = pts[w0 + lane];
            float d;
            {
                const float ddx = __fsub_rn(qx, pp.x);
                const float ddy = __fsub_rn(qy, pp.y);
                const float ddz = __fsub_rn(qz, pp.z);
                d = __fadd_rn(__fadd_rn(__fmul_rn(ddx, ddx), __fmul_rn(ddy, ddy)),
                              __fmul_rn(ddz, ddz));
            }
            int oi = __float_as_int(pp.w);
#pragma unroll
            for (int k = 2; k <= 64; k <<= 1) {
#pragma unroll
                for (int j = k >> 1; j >= 1; j >>= 1) {
                    const float od = __shfl_xor(d, j);
                    const int  ooi = __shfl_xor(oi, j);
                    const bool wantMin = (((lane & j) == 0) == ((lane & k) == 0));
                    const bool take = wantMin ? lexlt(od, ooi, d, oi)
                                              : lexlt(d, oi, od, ooi);
                    if (take) { d = od; oi = ooi; }
                }
            }
#pragma unroll
            for (int t = 0; t < KNN; ++t) {
                dq[t] = __shfl(d, t);
                iq[t] = __shfl(oi, t);
            }
        }

        float pd = 3.0e38f; int poi = 0x7fffffff; int cnum = 0;

        // ---- ring 0: center cell ----
        {
            const int2 hc = hb[(cz * G + cy) * G + cx];
            wave_append(pts, hc.x, hc.x + hc.y, w0, qx, qy, qz, lane, pd, poi, cnum, dq, iq);
        }
        wave_flush(pd, poi, cnum, lane, dq, iq);

        for (int R = 1; R < G; ++R) {
            // termination: processed box = rings 0..R-1
            {
                const int rm = R - 1;
                float dmin = 3.0e38f;
                bool any = false;
                if (cx - rm > 0)     { dmin = fminf(dmin, qx - (GORIG + (cx - rm) * GW)); any = true; }
                if (cx + rm < G - 1) { dmin = fminf(dmin, (GORIG + (cx + rm + 1) * GW) - qx); any = true; }
                if (cy - rm > 0)     { dmin = fminf(dmin, qy - (GORIG + (cy - rm) * GW)); any = true; }
                if (cy + rm < G - 1) { dmin = fminf(dmin, (GORIG + (cy + rm + 1) * GW) - qy); any = true; }
                if (cz - rm > 0)     { dmin = fminf(dmin, qz - (GORIG + (cz - rm) * GW)); any = true; }
                if (cz + rm < G - 1) { dmin = fminf(dmin, (GORIG + (cz + rm + 1) * GW) - qz); any = true; }
                if (!any) break;
                dmin = fmaxf(dmin, 0.0f);
                if (dq[KNN - 1] < dmin * dmin * (1.0f - 1e-5f)) break;
            }
            const int z0 = max(0, cz - R), z1 = min(G - 1, cz + R);
            const int y0 = max(0, cy - R), y1 = min(G - 1, cy + R);
            const int x0 = max(0, cx - R), x1 = min(G - 1, cx + R);
            const unsigned long long xm_full = (~0ull >> (63 - (x1 - x0))) << x0;

            for (int z = z0; z <= z1; ++z) {
                const int az = (z > cz) ? (z - cz) : (cz - z);
                const float dzc = axdist(qz, z);
                const float dz2 = dzc * dzc;
                if (dz2 * (1.0f - 1e-5f) > dq[KNN - 1]) continue;
                for (int y = y0; y <= y1; ++y) {
                    const int ay = (y > cy) ? (y - cy) : (cy - y);
                    const float dyc = axdist(qy, y);
                    const float dzy = dz2 + dyc * dyc;
                    if (dzy * (1.0f - 1e-5f) > dq[KNN - 1]) continue;
                    const int row = z * G + y;

                    unsigned long long m;
                    if (az == R || ay == R) {
                        m = xm_full;
                    } else {
                        m = 0ull;
                        if (cx - R >= 0) m |= 1ull << (cx - R);
                        if (cx + R < G)  m |= 1ull << (cx + R);
                    }
                    m &= (unsigned long long)socc[row * 2] |
                         ((unsigned long long)socc[row * 2 + 1] << 32);

                    while (m) {
                        const int x = __ffsll(m) - 1;
                        m &= m - 1;
                        const float dxc = axdist(qx, x);
                        const float cmin = dzy + dxc * dxc;
                        if (cmin * (1.0f - 1e-5f) > dq[KNN - 1]) continue;
                        const int2 hc = hb[row * G + x];
                        wave_append(pts, hc.x, hc.x + hc.y, w0, qx, qy, qz, lane,
                                    pd, poi, cnum, dq, iq);
                    }
                }
            }
            wave_flush(pd, poi, cnum, lane, dq, iq);   // dq current before next check
        }

        if (lane == 0) {
            int* op = idx_out + ((size_t)b * NPTS + qi) * KNN;
            ((int4*)op)[0] = make_int4(iq[0], iq[1], iq[2], iq[3]);
            ((int4*)op)[1] = make_int4(iq[4], iq[5], iq[6], iq[7]);
            ((int4*)op)[2] = make_int4(iq[8], iq[9], iq[10], iq[11]);
            ((int4*)op)[3] = make_int4(iq[12], iq[13], iq[14], iq[15]);
        }
    }
}

// ---------------------------------------------------------------------------
// 3) gather + Laplacian dx + 1x1 conv + relu + BN partial sums.
__global__ __launch_bounds__(128) void conv_kernel(const float* __restrict__ xt,
                                                   const int* __restrict__ idx,
                                                   const float* __restrict__ W,
                                                   const float* __restrict__ bias,
                                                   float* __restrict__ h_t,
                                                   float* __restrict__ partials) {
    __shared__ __align__(16) float dxbuf[CH];
    const int o   = threadIdx.x;
    const int blk = blockIdx.x;                  // 0..4095
    const int b   = blk / (NPTS / 16);
    const int n0  = (blk % (NPTS / 16)) * 16;

    float4 w4[CH / 4];
    const float4* wrow = (const float4*)(W + (size_t)o * CH);
#pragma unroll
    for (int i = 0; i < CH / 4; ++i) w4[i] = wrow[i];
    const float bo = bias[o];

    const float* xb = xt + (size_t)b * NPTS * CH;
    float sS = 0.0f, sQ = 0.0f;

    for (int r = 0; r < 16; ++r) {
        const int n = n0 + r;
        const int* ip = idx + ((size_t)b * NPTS + n) * KNN;
        int jj[KNN];
#pragma unroll
        for (int k = 0; k < KNN; ++k) jj[k] = ip[k];
        float va[KNN];
#pragma unroll
        for (int k = 0; k < KNN; ++k) va[k] = xb[(size_t)jj[k] * CH + o];
        const float ctr = xb[(size_t)n * CH + o];
        float acc = 0.0f;
#pragma unroll
        for (int k = 0; k < KNN; ++k) acc += va[k];
        acc -= ctr;

        dxbuf[o] = acc;
        __syncthreads();

        float h = bo;
        const float4* d4 = (const float4*)dxbuf;
#pragma unroll
        for (int cc = 0; cc < CH / 4; ++cc) {
            const float4 a = d4[cc];
            const float4 w = w4[cc];
            h = fmaf(w.x, a.x, h);
            h = fmaf(w.y, a.y, h);
            h = fmaf(w.z, a.z, h);
            h = fmaf(w.w, a.w, h);
        }
        h = fmaxf(h, 0.0f);
        h_t[((size_t)b * NPTS + n) * CH + o] = h;
        sS += h;
        sQ += h * h;
        __syncthreads();
    }

    partials[(size_t)o * 4096 + blk]        = sS;
    partials[(size_t)(CH + o) * 4096 + blk] = sQ;
}

// ---------------------------------------------------------------------------
// 4) reduce partials -> mean / rstd per channel (deterministic)
__global__ __launch_bounds__(256) void bnred_kernel(const float* __restrict__ partials,
                                                    float* __restrict__ stats) {
    const int ch = blockIdx.x;   // 0..127
    const float* pS = partials + (size_t)ch * 4096;
    const float* pQ = partials + (size_t)(CH + ch) * 4096;
    float s = 0.0f, q = 0.0f;
    for (int i = threadIdx.x; i < 4096; i += 256) { s += pS[i]; q += pQ[i]; }
#pragma unroll
    for (int off = 32; off > 0; off >>= 1) {
        s += __shfl_down(s, off);
        q += __shfl_down(q, off);
    }
    __shared__ float wsum[4][2];
    const int wid = threadIdx.x >> 6;
    if ((threadIdx.x & 63) == 0) { wsum[wid][0] = s; wsum[wid][1] = q; }
    __syncthreads();
    if (threadIdx.x == 0) {
        const float S = wsum[0][0] + wsum[1][0] + wsum[2][0] + wsum[3][0];
        const float Q = wsum[0][1] + wsum[1][1] + wsum[2][1] + wsum[3][1];
        const float inv  = 1.0f / (float)(BATCH * NPTS);
        const float mean = S * inv;
        const float var  = Q * inv - mean * mean;
        stats[ch]      = mean;
        stats[CH + ch] = rsqrtf(var + 1e-5f);
    }
}

// ---------------------------------------------------------------------------
// 5) out[b,c,n] = x + gamma*(h - mean)*rstd + beta   (h stored [B,N,CH])
__global__ __launch_bounds__(256) void final_kernel(const float* __restrict__ x,
                                                    const float* __restrict__ h_t,
                                                    const float* __restrict__ stats,
                                                    const float* __restrict__ gamma,
                                                    const float* __restrict__ beta,
                                                    float* __restrict__ out) {
    __shared__ float t[32][33];
    const int b  = blockIdx.z;
    const int o0 = blockIdx.y * 32;
    const int n0 = blockIdx.x * 32;
    const int tx = threadIdx.x, ty = threadIdx.y;   // block (32,8)
#pragma unroll
    for (int i = 0; i < 4; ++i)
        t[ty + 8 * i][tx] = h_t[((size_t)b * NPTS + n0 + ty + 8 * i) * CH + o0 + tx];
    __syncthreads();
#pragma unroll
    for (int i = 0; i < 4; ++i) {
        const int o = o0 + ty + 8 * i;
        const float mean = stats[o];
        const float rstd = stats[CH + o];
        const float g = gamma[o], be = beta[o];
        const size_t offp = ((size_t)b * CH + o) * NPTS + n0 + tx;
        out[offp] = x[offp] + g * ((t[tx][ty + 8 * i] - mean) * rstd) + be;
    }
}

// ---------------------------------------------------------------------------
extern "C" void kernel_launch(void* const* d_in, const int* in_sizes, int n_in,
                              void* d_out, int out_size, void* d_ws, size_t ws_size,
                              hipStream_t stream) {
    const float* xyz    = (const float*)d_in[0];
    const float* x      = (const float*)d_in[1];
    const float* conv_w = (const float*)d_in[2];
    const float* conv_b = (const float*)d_in[3];
    const float* gamma  = (const float*)d_in[4];
    const float* beta   = (const float*)d_in[5];
    float* out = (float*)d_out;

    char* ws = (char*)d_ws;
    float*        xt     = (float*)(ws + XT_OFF);
    int*          counts = (int*)  (ws + CNT_OFF);
    int*          cursor = (int*)  (ws + CUR_OFF);
    int2*         hdr    = (int2*) (ws + HDR_OFF);
    unsigned int* occ    = (unsigned int*)(ws + OCC_OFF);
    float4*       spts   = (float4*)(ws + SPTS_OFF);
    int*          gctr   = (int*)  (ws + GCTR_OFF);
    float*        h_t    = (float*)(ws + HT_OFF);
    int*          idx    = (int*)  (ws + IDX_OFF);
    float*        part   = (float*)(ws + PART_OFF);
    float*        stats  = (float*)(ws + STATS_OFF);

    // feature transpose (independent of grid work)
    transpose_kernel<<<dim3(NPTS / 32, CH / 32, BATCH), dim3(32, 8), 0, stream>>>(x, xt);

    // grid build
    zero_kernel<<<dim3(2048), dim3(256), 0, stream>>>(counts, 2 * BATCH * GRID3, gctr);
    count_kernel<<<dim3(NPTS / 256, BATCH), dim3(256), 0, stream>>>(xyz, counts);
    cellhdr_kernel<<<dim3(BATCH * GRID3 / 256), dim3(256), 0, stream>>>(counts, hdr, occ, gctr);
    scatter_kernel<<<dim3(NPTS / 256, BATCH), dim3(256), 0, stream>>>(xyz, hdr, cursor, spts);

    // exact knn: one query per wave, register-resident state
    knn_wave_kernel<<<dim3(QWAVES / 4, BATCH), dim3(256), 0, stream>>>(spts, hdr, occ, idx);

    // gather + conv + relu + partial BN sums (overwrites grid region with h_t)
    conv_kernel<<<dim3(BATCH * NPTS / 16), dim3(128), 0, stream>>>(xt, idx, conv_w, conv_b, h_t, part);
    bnred_kernel<<<dim3(CH), dim3(256), 0, stream>>>(part, stats);
    final_kernel<<<dim3(NPTS / 32, CH / 32, BATCH), dim3(32, 8), 0, stream>>>(x, h_t, stats, gamma, beta, out);
}

// Round 12
// 1194.015 us; speedup vs baseline: 1.6564x; 1.6564x over previous
//
#include <hip/hip_runtime.h>

#define BATCH 4
#define NPTS  16384
#define CH    128
#define KNN   16

// ---- fine grid: 64^3 cells of 0.25 ----
#define G      64
#define GRID3  (G * G * G)          // 262144 cells per batch (= 2^18)
#define GW     0.25f
#define GINVW  4.0f
#define GORIG  (-8.0f)
#define OCCW   (GRID3 / 32)         // 8192 occupancy words per batch

#define DENSE_THR 24                // 3^3-neighborhood count >= THR -> thread kernel

// ---------------- workspace layout (bytes) ----------------
#define XT_OFF    0
#define HT_OFF    33554432
#define CNT_OFF   33554432
#define CUR_OFF   37748736
#define HDR_OFF   41943040
#define OCC_OFF   50331648
#define SPTS_OFF  50462720
#define GCTR_OFF  51511296          // gctr[0..3] alloc, scnt = gctr+4
#define SLIST_OFF 51512320          // [B][NPTS] int
#define FLAG_OFF  51774464          // [B][NPTS] int
#define IDX_OFF   67108864
#define PART_OFF  71303168
#define STATS_OFF 75497472

__device__ __forceinline__ int cell1(float v) {
    int c = (int)floorf((v - GORIG) * GINVW);
    return min(G - 1, max(0, c));
}

__device__ __forceinline__ float axdist(float q, int c) {
    const float lo = GORIG + c * GW;
    return fmaxf(fmaxf(lo - q, q - (lo + GW)), 0.0f);
}

__device__ __forceinline__ bool lexlt(float d1, int i1, float d2, int i2) {
    return (d1 < d2) || (d1 == d2 && i1 < i2);
}

// guarded sorted insert (safe to call unconditionally)
__device__ __forceinline__ void insert_lex(float (&dq)[KNN], int (&iq)[KNN], float d, int oi) {
    if (!lexlt(d, oi, dq[KNN - 1], iq[KNN - 1])) return;
    float cd = d; int ci = oi;
#pragma unroll
    for (int t = KNN - 1; t >= 1; --t) {
        if (lexlt(cd, ci, dq[t - 1], iq[t - 1])) {
            dq[t] = dq[t - 1]; iq[t] = iq[t - 1];
            if (t == 1) { dq[0] = cd; iq[0] = ci; }
        } else {
            dq[t] = cd; iq[t] = ci;
            break;
        }
    }
}

// per-thread cell scan (thread-per-query kernel)
__device__ __forceinline__ void scan_cell(const float4* __restrict__ pts, int st, int en,
                                          float qx, float qy, float qz,
                                          float (&dq)[KNN], int (&iq)[KNN]) {
    for (int j = st; j < en; ++j) {
        const float4 pp = pts[j];
        const float ddx = __fsub_rn(qx, pp.x);
        const float ddy = __fsub_rn(qy, pp.y);
        const float ddz = __fsub_rn(qz, pp.z);
        const float d = __fadd_rn(__fadd_rn(__fmul_rn(ddx, ddx), __fmul_rn(ddy, ddy)),
                                  __fmul_rn(ddz, ddz));
        insert_lex(dq, iq, d, __float_as_int(pp.w));
    }
}

// ---- wave-cooperative helpers (sparse kernel; proven in R11) ----
__device__ __forceinline__ void wave_flush(float& pd, int& poi, int& cnum, int lane,
                                           float (&dq)[KNN], int (&iq)[KNN]) {
    if (cnum == 0) return;
#pragma unroll
    for (int it = 0; it < KNN; ++it) {
        float md = pd; int mi = poi; int ml = lane;
#pragma unroll
        for (int off = 1; off < 64; off <<= 1) {
            const float od = __shfl_xor(md, off);
            const int  omi = __shfl_xor(mi, off);
            const int  oml = __shfl_xor(ml, off);
            if (lexlt(od, omi, md, mi)) { md = od; mi = omi; ml = oml; }
        }
        if (!lexlt(md, mi, dq[KNN - 1], iq[KNN - 1])) break;
        insert_lex(dq, iq, md, mi);
        if (lane == ml) { pd = 3.0e38f; poi = 0x7fffffff; }
    }
    pd = 3.0e38f; poi = 0x7fffffff;   // remainder provably lex->= dq[15]
    cnum = 0;
}

__device__ __forceinline__ void wave_append(const float4* __restrict__ pts,
                                            int a0, int e0,
                                            float qx, float qy, float qz, int lane,
                                            float& pd, int& poi, int& cnum,
                                            float (&dq)[KNN], int (&iq)[KNN]) {
    int a = a0;
    int c = e0 - a0;
    while (c > 0) {
        const int t = min(c, 64 - cnum);
        if (lane >= cnum && lane < cnum + t) {
            const float4 pp = pts[a + lane - cnum];
            const float ddx = __fsub_rn(qx, pp.x);
            const float ddy = __fsub_rn(qy, pp.y);
            const float ddz = __fsub_rn(qz, pp.z);
            pd  = __fadd_rn(__fadd_rn(__fmul_rn(ddx, ddx), __fmul_rn(ddy, ddy)),
                            __fmul_rn(ddz, ddz));
            poi = __float_as_int(pp.w);
        }
        c -= t; a += t; cnum += t;
        if (cnum == 64) wave_flush(pd, poi, cnum, lane, dq, iq);
    }
}

// ---------------------------------------------------------------------------
// 0) zero grid counters (counts+cursor contiguous) + gctr/scnt
__global__ __launch_bounds__(256) void zero_kernel(int* __restrict__ p, int n,
                                                   int* __restrict__ gctr) {
    int i = blockIdx.x * 256 + threadIdx.x;
    if (i < 2 * BATCH) gctr[i] = 0;
    const int stride = gridDim.x * 256;
    for (; i < n; i += stride) p[i] = 0;
}

// ---------------------------------------------------------------------------
// 1) transpose x [B,CH,N] -> xt [B,N,CH]
__global__ __launch_bounds__(256) void transpose_kernel(const float* __restrict__ x,
                                                        float* __restrict__ xt) {
    __shared__ float t[32][33];
    const int b  = blockIdx.z;
    const int c0 = blockIdx.y * 32;
    const int n0 = blockIdx.x * 32;
    const int tx = threadIdx.x, ty = threadIdx.y;   // block (32,8)
#pragma unroll
    for (int i = 0; i < 4; ++i)
        t[ty + 8 * i][tx] = x[((size_t)b * CH + c0 + ty + 8 * i) * NPTS + n0 + tx];
    __syncthreads();
#pragma unroll
    for (int i = 0; i < 4; ++i)
        xt[((size_t)b * NPTS + n0 + ty + 8 * i) * CH + c0 + tx] = t[tx][ty + 8 * i];
}

// ---------------------------------------------------------------------------
// 2a) count points per cell (linear cid = (z*G+y)*G+x)
__global__ __launch_bounds__(256) void count_kernel(const float* __restrict__ xyz,
                                                    int* __restrict__ counts) {
    const int b = blockIdx.y;
    const int i = blockIdx.x * 256 + threadIdx.x;
    const float* p = xyz + ((size_t)b * NPTS + i) * 3;
    const int c = (cell1(p[2]) * G + cell1(p[1])) * G + cell1(p[0]);
    atomicAdd(&counts[((size_t)b << 18) + c], 1);
}

// 2b) per-cell (start,count) headers + z-major occupancy
__global__ __launch_bounds__(256) void cellhdr_kernel(const int* __restrict__ counts,
                                                      int2* __restrict__ hdr,
                                                      unsigned int* __restrict__ occ,
                                                      int* __restrict__ gctr) {
    const int cid  = blockIdx.x * 256 + threadIdx.x;
    const int b    = cid >> 18;
    const int lane = threadIdx.x & 63;
    const int c    = counts[cid];

    int incl = c;
#pragma unroll
    for (int off = 1; off < 64; off <<= 1) {
        int t = __shfl_up(incl, off);
        if (lane >= off) incl += t;
    }
    const int excl = incl - c;
    const int tot  = __shfl(incl, 63);

    const unsigned long long ball = __ballot(c > 0);
    if (lane == 0) {
        const int w = cid >> 5;
        occ[w]     = (unsigned int)ball;
        occ[w + 1] = (unsigned int)(ball >> 32);
    }

    int base = 0;
    if (lane == 63) base = atomicAdd(&gctr[b], tot);
    base = __shfl(base, 63);

    if (c > 0) hdr[cid] = make_int2(base + excl, c);
}

// 2c) scatter points into cell-grouped order, original idx in .w
__global__ __launch_bounds__(256) void scatter_kernel(const float* __restrict__ xyz,
                                                      const int2* __restrict__ hdr,
                                                      int* __restrict__ cursor,
                                                      float4* __restrict__ spts) {
    const int b = blockIdx.y;
    const int i = blockIdx.x * 256 + threadIdx.x;
    const float* p = xyz + ((size_t)b * NPTS + i) * 3;
    const float x = p[0], y = p[1], z = p[2];
    const int c = (cell1(z) * G + cell1(y)) * G + cell1(x);
    const int pos = hdr[((size_t)b << 18) + c].x + atomicAdd(&cursor[((size_t)b << 18) + c], 1);
    spts[(size_t)b * NPTS + pos] = make_float4(x, y, z, __int_as_float(i));
}

// 2d) density flag per sorted slot: 3^3 neighborhood count >= THR -> dense
__global__ __launch_bounds__(256) void flag_kernel(const float4* __restrict__ spts,
                                                   const int* __restrict__ counts,
                                                   int* __restrict__ flags,
                                                   int* __restrict__ slist,
                                                   int* __restrict__ scnt) {
    const int b = blockIdx.y;
    const int s = blockIdx.x * 256 + threadIdx.x;
    const float4 P = spts[(size_t)b * NPTS + s];
    const int cx = cell1(P.x), cy = cell1(P.y), cz = cell1(P.z);
    const int* cb = counts + ((size_t)b << 18);
    int sum = 0;
    const int z0 = max(0, cz - 1), z1 = min(G - 1, cz + 1);
    const int y0 = max(0, cy - 1), y1 = min(G - 1, cy + 1);
    const int x0 = max(0, cx - 1), x1 = min(G - 1, cx + 1);
    for (int z = z0; z <= z1; ++z)
        for (int y = y0; y <= y1; ++y)
            for (int x = x0; x <= x1; ++x)
                sum += cb[(z * G + y) * G + x];
    const int dense = (sum >= DENSE_THR) ? 1 : 0;
    flags[(size_t)b * NPTS + s] = dense;
    if (!dense) {
        const int pos = atomicAdd(&scnt[b], 1);
        slist[(size_t)b * NPTS + pos] = s;
    }
}

// ---------------------------------------------------------------------------
// 2e) dense queries: thread-per-query ring walk (R4-proven, tail removed)
__global__ __launch_bounds__(256) void knn_thread_kernel(const float4* __restrict__ spts,
                                                         const int2* __restrict__ hdr,
                                                         const unsigned int* __restrict__ occ,
                                                         const int* __restrict__ flags,
                                                         int* __restrict__ idx_out) {
    __shared__ unsigned int socc[OCCW];    // 32 KB occupancy
    const int b   = blockIdx.y;
    const int tid = threadIdx.x;
    for (int i = tid; i < OCCW; i += 256) socc[i] = occ[(size_t)b * OCCW + i];
    __syncthreads();

    const int s = blockIdx.x * 256 + tid;
    if (!flags[(size_t)b * NPTS + s]) return;      // sparse -> other kernel

    const float4 P = spts[(size_t)b * NPTS + s];
    const float qx = P.x, qy = P.y, qz = P.z;
    const int qi = __float_as_int(P.w);
    const int cx = cell1(qx), cy = cell1(qy), cz = cell1(qz);
    const int2* hb = hdr + ((size_t)b << 18);
    const float4* pts = spts + (size_t)b * NPTS;

    float dq[KNN]; int iq[KNN];
#pragma unroll
    for (int t = 0; t < KNN; ++t) { dq[t] = 3.0e38f; iq[t] = 0x7fffffff; }

    {
        const int2 hc = hb[(cz * G + cy) * G + cx];
        scan_cell(pts, hc.x, hc.x + hc.y, qx, qy, qz, dq, iq);
    }

    for (int R = 1; R < G; ++R) {
        {
            const int rm = R - 1;
            float dmin = 3.0e38f;
            bool any = false;
            if (cx - rm > 0)     { dmin = fminf(dmin, qx - (GORIG + (cx - rm) * GW)); any = true; }
            if (cx + rm < G - 1) { dmin = fminf(dmin, (GORIG + (cx + rm + 1) * GW) - qx); any = true; }
            if (cy - rm > 0)     { dmin = fminf(dmin, qy - (GORIG + (cy - rm) * GW)); any = true; }
            if (cy + rm < G - 1) { dmin = fminf(dmin, (GORIG + (cy + rm + 1) * GW) - qy); any = true; }
            if (cz - rm > 0)     { dmin = fminf(dmin, qz - (GORIG + (cz - rm) * GW)); any = true; }
            if (cz + rm < G - 1) { dmin = fminf(dmin, (GORIG + (cz + rm + 1) * GW) - qz); any = true; }
            if (!any) break;
            dmin = fmaxf(dmin, 0.0f);
            if (dq[KNN - 1] < dmin * dmin * (1.0f - 1e-5f)) break;
        }
        const int z0 = max(0, cz - R), z1 = min(G - 1, cz + R);
        const int y0 = max(0, cy - R), y1 = min(G - 1, cy + R);
        const int x0 = max(0, cx - R), x1 = min(G - 1, cx + R);
        for (int z = z0; z <= z1; ++z) {
            const int az = (z > cz) ? (z - cz) : (cz - z);
            const float dzc = axdist(qz, z);
            const float dz2 = dzc * dzc;
            for (int y = y0; y <= y1; ++y) {
                const int ay = (y > cy) ? (y - cy) : (cy - y);
                const float dyc = axdist(qy, y);
                const float dzy = dz2 + dyc * dyc;
                const int row = z * G + y;

                unsigned long long m;
                if (az == R || ay == R) {
                    m = (~0ull >> (63 - (x1 - x0))) << x0;
                } else {
                    m = 0ull;
                    if (cx - R >= 0) m |= 1ull << (cx - R);
                    if (cx + R < G)  m |= 1ull << (cx + R);
                }
                m &= (unsigned long long)socc[row * 2] |
                     ((unsigned long long)socc[row * 2 + 1] << 32);

                while (m) {
                    const int x = __ffsll(m) - 1;
                    m &= m - 1;
                    const float dxc = axdist(qx, x);
                    const float cmin = dzy + dxc * dxc;
                    if (cmin * (1.0f - 1e-5f) > dq[KNN - 1]) continue;
                    const int2 hc = hb[row * G + x];
                    scan_cell(pts, hc.x, hc.x + hc.y, qx, qy, qz, dq, iq);
                }
            }
        }
    }

    int* op = idx_out + ((size_t)b * NPTS + qi) * KNN;
#pragma unroll
    for (int t = 0; t < KNN; ++t) op[t] = iq[t];
}

// ---------------------------------------------------------------------------
// 2f) sparse queries: wave-per-query (divergence-free; R11-proven machinery)
__global__ __launch_bounds__(256) void knn_sparse_kernel(const float4* __restrict__ spts,
                                                         const int2* __restrict__ hdr,
                                                         const unsigned int* __restrict__ occ,
                                                         const int* __restrict__ slist,
                                                         const int* __restrict__ scnt,
                                                         int* __restrict__ idx_out) {
    __shared__ unsigned int socc[OCCW];    // 32 KB occupancy
    const int b   = blockIdx.y;
    const int tid = threadIdx.x;
    for (int i = tid; i < OCCW; i += 256) socc[i] = occ[(size_t)b * OCCW + i];
    __syncthreads();

    const int widx = tid >> 6;
    const int lane = tid & 63;
    const int nw   = gridDim.x * 4;                  // waves per batch
    const int wid0 = blockIdx.x * 4 + widx;
    const int cnt  = scnt[b];
    const int2* hb = hdr + ((size_t)b << 18);
    const float4* pts = spts + (size_t)b * NPTS;

    for (int li = wid0; li < cnt; li += nw) {
        const int s = slist[(size_t)b * NPTS + li];
        const float4 P = pts[s];
        const float qx = P.x, qy = P.y, qz = P.z;
        const int qi = __float_as_int(P.w);
        const int cx = cell1(qx), cy = cell1(qy), cz = cell1(qz);

        float dq[KNN]; int iq[KNN];
#pragma unroll
        for (int t = 0; t < KNN; ++t) { dq[t] = 3.0e38f; iq[t] = 0x7fffffff; }

        float pd = 3.0e38f; int poi = 0x7fffffff; int cnum = 0;

        {
            const int2 hc = hb[(cz * G + cy) * G + cx];
            wave_append(pts, hc.x, hc.x + hc.y, qx, qy, qz, lane, pd, poi, cnum, dq, iq);
        }
        wave_flush(pd, poi, cnum, lane, dq, iq);

        for (int R = 1; R < G; ++R) {
            {
                const int rm = R - 1;
                float dmin = 3.0e38f;
                bool any = false;
                if (cx - rm > 0)     { dmin = fminf(dmin, qx - (GORIG + (cx - rm) * GW)); any = true; }
                if (cx + rm < G - 1) { dmin = fminf(dmin, (GORIG + (cx + rm + 1) * GW) - qx); any = true; }
                if (cy - rm > 0)     { dmin = fminf(dmin, qy - (GORIG + (cy - rm) * GW)); any = true; }
                if (cy + rm < G - 1) { dmin = fminf(dmin, (GORIG + (cy + rm + 1) * GW) - qy); any = true; }
                if (cz - rm > 0)     { dmin = fminf(dmin, qz - (GORIG + (cz - rm) * GW)); any = true; }
                if (cz + rm < G - 1) { dmin = fminf(dmin, (GORIG + (cz + rm + 1) * GW) - qz); any = true; }
                if (!any) break;
                dmin = fmaxf(dmin, 0.0f);
                if (dq[KNN - 1] < dmin * dmin * (1.0f - 1e-5f)) break;
            }
            const int z0 = max(0, cz - R), z1 = min(G - 1, cz + R);
            const int y0 = max(0, cy - R), y1 = min(G - 1, cy + R);
            const int x0 = max(0, cx - R), x1 = min(G - 1, cx + R);
            const unsigned long long xm_full = (~0ull >> (63 - (x1 - x0))) << x0;

            for (int z = z0; z <= z1; ++z) {
                const int az = (z > cz) ? (z - cz) : (cz - z);
                const float dzc = axdist(qz, z);
                const float dz2 = dzc * dzc;
                if (dz2 * (1.0f - 1e-5f) > dq[KNN - 1]) continue;
                for (int y = y0; y <= y1; ++y) {
                    const int ay = (y > cy) ? (y - cy) : (cy - y);
                    const float dyc = axdist(qy, y);
                    const float dzy = dz2 + dyc * dyc;
                    if (dzy * (1.0f - 1e-5f) > dq[KNN - 1]) continue;
                    const int row = z * G + y;

                    unsigned long long m;
                    if (az == R || ay == R) {
                        m = xm_full;
                    } else {
                        m = 0ull;
                        if (cx - R >= 0) m |= 1ull << (cx - R);
                        if (cx + R < G)  m |= 1ull << (cx + R);
                    }
                    m &= (unsigned long long)socc[row * 2] |
                         ((unsigned long long)socc[row * 2 + 1] << 32);

                    while (m) {
                        const int x = __ffsll(m) - 1;
                        m &= m - 1;
                        const float dxc = axdist(qx, x);
                        const float cmin = dzy + dxc * dxc;
                        if (cmin * (1.0f - 1e-5f) > dq[KNN - 1]) continue;
                        const int2 hc = hb[row * G + x];
                        wave_append(pts, hc.x, hc.x + hc.y, qx, qy, qz, lane,
                                    pd, poi, cnum, dq, iq);
                    }
                }
            }
            wave_flush(pd, poi, cnum, lane, dq, iq);
        }

        if (lane == 0) {
            int* op = idx_out + ((size_t)b * NPTS + qi) * KNN;
            ((int4*)op)[0] = make_int4(iq[0], iq[1], iq[2], iq[3]);
            ((int4*)op)[1] = make_int4(iq[4], iq[5], iq[6], iq[7]);
            ((int4*)op)[2] = make_int4(iq[8], iq[9], iq[10], iq[11]);
            ((int4*)op)[3] = make_int4(iq[12], iq[13], iq[14], iq[15]);
        }
    }
}

// ---------------------------------------------------------------------------
// 3) gather + Laplacian dx + 1x1 conv + relu + BN partial sums.
__global__ __launch_bounds__(128) void conv_kernel(const float* __restrict__ xt,
                                                   const int* __restrict__ idx,
                                                   const float* __restrict__ W,
                                                   const float* __restrict__ bias,
                                                   float* __restrict__ h_t,
                                                   float* __restrict__ partials) {
    __shared__ __align__(16) float dxbuf[CH];
    const int o   = threadIdx.x;
    const int blk = blockIdx.x;                  // 0..4095
    const int b   = blk / (NPTS / 16);
    const int n0  = (blk % (NPTS / 16)) * 16;

    float4 w4[CH / 4];
    const float4* wrow = (const float4*)(W + (size_t)o * CH);
#pragma unroll
    for (int i = 0; i < CH / 4; ++i) w4[i] = wrow[i];
    const float bo = bias[o];

    const float* xb = xt + (size_t)b * NPTS * CH;
    float sS = 0.0f, sQ = 0.0f;

    for (int r = 0; r < 16; ++r) {
        const int n = n0 + r;
        const int* ip = idx + ((size_t)b * NPTS + n) * KNN;
        int jj[KNN];
#pragma unroll
        for (int k = 0; k < KNN; ++k) jj[k] = ip[k];
        float va[KNN];
#pragma unroll
        for (int k = 0; k < KNN; ++k) va[k] = xb[(size_t)jj[k] * CH + o];
        const float ctr = xb[(size_t)n * CH + o];
        float acc = 0.0f;
#pragma unroll
        for (int k = 0; k < KNN; ++k) acc += va[k];
        acc -= ctr;

        dxbuf[o] = acc;
        __syncthreads();

        float h = bo;
        const float4* d4 = (const float4*)dxbuf;
#pragma unroll
        for (int cc = 0; cc < CH / 4; ++cc) {
            const float4 a = d4[cc];
            const float4 w = w4[cc];
            h = fmaf(w.x, a.x, h);
            h = fmaf(w.y, a.y, h);
            h = fmaf(w.z, a.z, h);
            h = fmaf(w.w, a.w, h);
        }
        h = fmaxf(h, 0.0f);
        h_t[((size_t)b * NPTS + n) * CH + o] = h;
        sS += h;
        sQ += h * h;
        __syncthreads();
    }

    partials[(size_t)o * 4096 + blk]        = sS;
    partials[(size_t)(CH + o) * 4096 + blk] = sQ;
}

// ---------------------------------------------------------------------------
// 4) reduce partials -> mean / rstd per channel (deterministic)
__global__ __launch_bounds__(256) void bnred_kernel(const float* __restrict__ partials,
                                                    float* __restrict__ stats) {
    const int ch = blockIdx.x;   // 0..127
    const float* pS = partials + (size_t)ch * 4096;
    const float* pQ = partials + (size_t)(CH + ch) * 4096;
    float s = 0.0f, q = 0.0f;
    for (int i = threadIdx.x; i < 4096; i += 256) { s += pS[i]; q += pQ[i]; }
#pragma unroll
    for (int off = 32; off > 0; off >>= 1) {
        s += __shfl_down(s, off);
        q += __shfl_down(q, off);
    }
    __shared__ float wsum[4][2];
    const int wid = threadIdx.x >> 6;
    if ((threadIdx.x & 63) == 0) { wsum[wid][0] = s; wsum[wid][1] = q; }
    __syncthreads();
    if (threadIdx.x == 0) {
        const float S = wsum[0][0] + wsum[1][0] + wsum[2][0] + wsum[3][0];
        const float Q = wsum[0][1] + wsum[1][1] + wsum[2][1] + wsum[3][1];
        const float inv  = 1.0f / (float)(BATCH * NPTS);
        const float mean = S * inv;
        const float var  = Q * inv - mean * mean;
        stats[ch]      = mean;
        stats[CH + ch] = rsqrtf(var + 1e-5f);
    }
}

// ---------------------------------------------------------------------------
// 5) out[b,c,n] = x + gamma*(h - mean)*rstd + beta   (h stored [B,N,CH])
__global__ __launch_bounds__(256) void final_kernel(const float* __restrict__ x,
                                                    const float* __restrict__ h_t,
                                                    const float* __restrict__ stats,
                                                    const float* __restrict__ gamma,
                                                    const float* __restrict__ beta,
                                                    float* __restrict__ out) {
    __shared__ float t[32][33];
    const int b  = blockIdx.z;
    const int o0 = blockIdx.y * 32;
    const int n0 = blockIdx.x * 32;
    const int tx = threadIdx.x, ty = threadIdx.y;   // block (32,8)
#pragma unroll
    for (int i = 0; i < 4; ++i)
        t[ty + 8 * i][tx] = h_t[((size_t)b * NPTS + n0 + ty + 8 * i) * CH + o0 + tx];
    __syncthreads();
#pragma unroll
    for (int i = 0; i < 4; ++i) {
        const int o = o0 + ty + 8 * i;
        const float mean = stats[o];
        const float rstd = stats[CH + o];
        const float g = gamma[o], be = beta[o];
        const size_t offp = ((size_t)b * CH + o) * NPTS + n0 + tx;
        out[offp] = x[offp] + g * ((t[tx][ty + 8 * i] - mean) * rstd) + be;
    }
}

// ---------------------------------------------------------------------------
extern "C" void kernel_launch(void* const* d_in, const int* in_sizes, int n_in,
                              void* d_out, int out_size, void* d_ws, size_t ws_size,
                              hipStream_t stream) {
    const float* xyz    = (const float*)d_in[0];
    const float* x      = (const float*)d_in[1];
    const float* conv_w = (const float*)d_in[2];
    const float* conv_b = (const float*)d_in[3];
    const float* gamma  = (const float*)d_in[4];
    const float* beta   = (const float*)d_in[5];
    float* out = (float*)d_out;

    char* ws = (char*)d_ws;
    float*        xt     = (float*)(ws + XT_OFF);
    int*          counts = (int*)  (ws + CNT_OFF);
    int*          cursor = (int*)  (ws + CUR_OFF);
    int2*         hdr    = (int2*) (ws + HDR_OFF);
    unsigned int* occ    = (unsigned int*)(ws + OCC_OFF);
    float4*       spts   = (float4*)(ws + SPTS_OFF);
    int*          gctr   = (int*)  (ws + GCTR_OFF);
    int*          scnt   = gctr + 4;
    int*          slist  = (int*)  (ws + SLIST_OFF);
    int*          flags  = (int*)  (ws + FLAG_OFF);
    float*        h_t    = (float*)(ws + HT_OFF);
    int*          idx    = (int*)  (ws + IDX_OFF);
    float*        part   = (float*)(ws + PART_OFF);
    float*        stats  = (float*)(ws + STATS_OFF);

    // feature transpose (independent of grid work)
    transpose_kernel<<<dim3(NPTS / 32, CH / 32, BATCH), dim3(32, 8), 0, stream>>>(x, xt);

    // grid build
    zero_kernel<<<dim3(2048), dim3(256), 0, stream>>>(counts, 2 * BATCH * GRID3, gctr);
    count_kernel<<<dim3(NPTS / 256, BATCH), dim3(256), 0, stream>>>(xyz, counts);
    cellhdr_kernel<<<dim3(BATCH * GRID3 / 256), dim3(256), 0, stream>>>(counts, hdr, occ, gctr);
    scatter_kernel<<<dim3(NPTS / 256, BATCH), dim3(256), 0, stream>>>(xyz, hdr, cursor, spts);

    // density partition
    flag_kernel<<<dim3(NPTS / 256, BATCH), dim3(256), 0, stream>>>(spts, counts, flags, slist, scnt);

    // exact knn: dense -> thread-per-query; sparse -> wave-per-query
    knn_thread_kernel<<<dim3(NPTS / 256, BATCH), dim3(256), 0, stream>>>(spts, hdr, occ, flags, idx);
    knn_sparse_kernel<<<dim3(256, BATCH), dim3(256), 0, stream>>>(spts, hdr, occ, slist, scnt, idx);

    // gather + conv + relu + partial BN sums (overwrites grid region with h_t)
    conv_kernel<<<dim3(BATCH * NPTS / 16), dim3(128), 0, stream>>>(xt, idx, conv_w, conv_b, h_t, part);
    bnred_kernel<<<dim3(CH), dim3(256), 0, stream>>>(part, stats);
    final_kernel<<<dim3(NPTS / 32, CH / 32, BATCH), dim3(32, 8), 0, stream>>>(x, h_t, stats, gamma, beta, out);
}